// Round 9
// baseline (3817.817 us; speedup 1.0000x reference)
//
#include <hip/hip_runtime.h>
#include <math.h>

#define B_ 128
#define T_ 512
#define V_ 256
#define H_ 512

typedef unsigned short u16;
typedef unsigned int u32;
typedef unsigned long long u64;
typedef __attribute__((ext_vector_type(8))) __bf16 bf16x8;
typedef __attribute__((ext_vector_type(4))) float f32x4;
typedef __attribute__((ext_vector_type(4))) u32 u32x4;

__device__ __forceinline__ float sigf(float x) { return 1.f / (1.f + __expf(-x)); }
__device__ __forceinline__ float tanh_fast(float x) {
    x = fminf(fmaxf(x, -15.f), 15.f);
    float e = __expf(2.f * x);
    return (e - 1.f) / (e + 1.f);
}
__device__ __forceinline__ u16 f2bf(float f) {
    union { float f; u32 u; } v; v.f = f;
    u32 r = v.u + 0x7FFFu + ((v.u >> 16) & 1u);
    return (u16)(r >> 16);
}

// proven cross-XCD visibility path: compiler-generated relaxed agent atomics
__device__ __forceinline__ u64 aload(const u64* p) {
    return __hip_atomic_load(p, __ATOMIC_RELAXED, __HIP_MEMORY_SCOPE_AGENT);
}
__device__ __forceinline__ void astore(u64* p, u64 v) {
    __hip_atomic_store(p, v, __ATOMIC_RELAXED, __HIP_MEMORY_SCOPE_AGENT);
}
__device__ __forceinline__ u32 aload32(const u32* p) {
    return __hip_atomic_load(p, __ATOMIC_RELAXED, __HIP_MEMORY_SCOPE_AGENT);
}
__device__ __forceinline__ void astore32(u32* p, u32 v) {
    __hip_atomic_store(p, v, __ATOMIC_RELAXED, __HIP_MEMORY_SCOPE_AGENT);
}
__device__ __forceinline__ void pollge(const u32* slots, int idx, int target) {
    const u32* p = slots + idx;
    for (;;) {
        u32 v = aload32(p);
        if (__all((int)v >= target)) break;
        __builtin_amdgcn_s_sleep(1);
    }
    __builtin_amdgcn_sched_barrier(0);
    asm volatile("" ::: "memory");
}
__device__ __forceinline__ bf16x8 afrag(const u16* p) {
    union { u64 d[2]; bf16x8 v; } u;
    u.d[0] = aload((const u64*)p);
    u.d[1] = aload((const u64*)(p + 4));
    return u.v;
}

// ---------- prep kernels (verified rounds 2-8) ----------
__global__ __launch_bounds__(256) void conv_x(u16* __restrict__ dst, const float* __restrict__ x) {
    int tid = blockIdx.x * 256 + threadIdx.x;
    int k = tid & (V_ - 1);
    int t = (tid >> 8) & (T_ - 1);
    int b = tid >> 17;
    float v = x[tid];
    int lane = (b & 15) | (((k >> 3) & 3) << 4);
    dst[((((size_t)t * 8 + (b >> 4)) * 8) + (k >> 5)) * 512 + (size_t)lane * 8 + (k & 7)] = f2bf(v);
}

__global__ __launch_bounds__(256) void conv_w(u16* __restrict__ dst,
                                              const float* __restrict__ wih,
                                              const float* __restrict__ whh,
                                              int KIN, int Ktot) {
    int tid = blockIdx.x * 256 + threadIdx.x;
    int n = tid / Ktot, k = tid - n * Ktot;
    float v = (k < KIN) ? wih[(size_t)n * KIN + k] : whh[(size_t)n * H_ + (k - KIN)];
    int lane = (n & 15) | (((k >> 3) & 3) << 4);
    dst[((size_t)((n >> 4) * (Ktot >> 5) + (k >> 5))) * 512 + (size_t)lane * 8 + (k & 7)] = f2bf(v);
}

__global__ __launch_bounds__(256) void vadd(float* __restrict__ d,
                                            const float* __restrict__ a,
                                            const float* __restrict__ b, int n) {
    int i = blockIdx.x * 256 + threadIdx.x;
    if (i < n) d[i] = a[i] + b[i];
}

// ---------- persistent recurrence ----------
// 256 blocks x 256 threads. blockIdx = js*8 + g, g = layer*4 + mq.
// Waves: wid 0,1 = A-role (m=wid): compute x/out0 part for step s+1 into
// scr[(s+1)&1] (one step AHEAD). wid 2,3 = H-role (m=wid-2): tagged-h poll
// (bulk load + per-kc retry), recurrent MFMAs (acc init from scr[s&1]),
// cell update, tagged h stores. ONE __syncthreads per step.
// h element = u32 (tag<<16 | bf16); u64 store => per-u64 tag consistency.
// h(t) tagged t+1 in buffer (t+1)&1; consumer at step s expects tag s.

template <int LAYER>
__device__ __forceinline__ void run_loop(
    const u16* __restrict__ Xswz, u16* __restrict__ Out0,
    const u16* __restrict__ WBs,          // LDS [4 g][KCT][512] bf16
    f32x4* __restrict__ scr,              // LDS [2 par][2 m][4 g][64]
    u16* __restrict__ tileb,              // LDS [2 m][16][20]
    u32* __restrict__ Hgrp,               // [2 buf][2 m][16 kc][512] tagged u32
    const float* __restrict__ bsum, float* __restrict__ out,
    u32* __restrict__ bc,                 // [2 m][32 js] (this mq)
    int js, int mq, int wid, int lane)
{
    constexpr int KCA = LAYER ? 16 : 8;
    constexpr int KCT = KCA + 16;
    const int m = wid & 1;
    const bool isA = wid < 2;
    const int jl = (js << 4) | (lane & 15);

    if (isA) {
        // ---------------- A-role: one step ahead ----------------
        for (int s = -1; s < T_; ++s) {
            const int tc = s + 1;
            if (tc < T_) {
                f32x4 acc[4];
                #pragma unroll
                for (int g = 0; g < 4; ++g) acc[g] = (f32x4){0.f, 0.f, 0.f, 0.f};
                if (LAYER == 0) {
                    const u16* As = Xswz + (size_t)tc * 32768 + (size_t)(2 * mq + m) * 4096 + (size_t)lane * 8;
                    #pragma unroll
                    for (int kc = 0; kc < 8; ++kc) {
                        bf16x8 a = *(const bf16x8*)(As + (size_t)kc * 512);
                        #pragma unroll
                        for (int g = 0; g < 4; ++g)
                            acc[g] = __builtin_amdgcn_mfma_f32_16x16x32_bf16(
                                a, *(const bf16x8*)(WBs + (size_t)(g * KCT + kc) * 512 + (size_t)lane * 8), acc[g], 0, 0, 0);
                    }
                } else {
                    pollge(bc + m * 32, lane & 31, tc + 1);   // out0(tc) ready
                    const u16* As = Out0 + (size_t)tc * 65536 + (size_t)(2 * mq + m) * 8192 + (size_t)lane * 8;
                    bf16x8 fa[16];
                    #pragma unroll
                    for (int kc = 0; kc < 16; ++kc) fa[kc] = afrag(As + (size_t)kc * 512);
                    #pragma unroll
                    for (int kc = 0; kc < 16; ++kc) {
                        #pragma unroll
                        for (int g = 0; g < 4; ++g)
                            acc[g] = __builtin_amdgcn_mfma_f32_16x16x32_bf16(
                                fa[kc], *(const bf16x8*)(WBs + (size_t)(g * KCT + kc) * 512 + (size_t)lane * 8), acc[g], 0, 0, 0);
                    }
                }
                #pragma unroll
                for (int g = 0; g < 4; ++g) scr[(size_t)(((tc & 1) * 2 + m) * 4 + g) * 64 + lane] = acc[g];
            }
            __syncthreads();
        }
    } else {
        // ---------------- H-role ----------------
        const float bi0 = bsum[jl], bi1 = bsum[512 + jl];
        const float bi2 = bsum[1024 + jl], bi3 = bsum[1536 + jl];
        f32x4 creg = {0.f, 0.f, 0.f, 0.f};
        u32* bcs = bc + m * 32 + js;

        for (int s = -1; s < T_; ++s) {
            if (s >= 0) {
                const u32 tag = (u32)s;
                const u32* hb = Hgrp + (size_t)(tag & 1) * 16384 + (size_t)m * 8192;
                u64 f[64];
                // bulk load (single pass, pipelined)
                #pragma unroll
                for (int kc = 0; kc < 16; ++kc) {
                    const u64* p = (const u64*)(hb + (size_t)kc * 512 + (size_t)lane * 8);
                    f[4 * kc + 0] = aload(p + 0);
                    f[4 * kc + 1] = aload(p + 1);
                    f[4 * kc + 2] = aload(p + 2);
                    f[4 * kc + 3] = aload(p + 3);
                }
                // per-kc bad mask (1 tag check per u64; u64 store is atomic)
                u32 bad = 0u;
                #pragma unroll
                for (int kc = 0; kc < 16; ++kc) {
                    u32 b = (((u32)(f[4 * kc + 0] >> 16) & 0xFFFFu) ^ tag)
                          | (((u32)(f[4 * kc + 1] >> 16) & 0xFFFFu) ^ tag)
                          | (((u32)(f[4 * kc + 2] >> 16) & 0xFFFFu) ^ tag)
                          | (((u32)(f[4 * kc + 3] >> 16) & 0xFFFFu) ^ tag);
                    bad |= b ? (1u << kc) : 0u;
                }
                // straggler retry: re-load only bad 512B chunks
                while (__any(bad != 0u)) {
                    #pragma unroll
                    for (int kc = 0; kc < 16; ++kc) {
                        if (bad & (1u << kc)) {
                            const u64* p = (const u64*)(hb + (size_t)kc * 512 + (size_t)lane * 8);
                            u64 g0 = aload(p + 0), g1 = aload(p + 1), g2 = aload(p + 2), g3 = aload(p + 3);
                            u32 b = (((u32)(g0 >> 16) & 0xFFFFu) ^ tag)
                                  | (((u32)(g1 >> 16) & 0xFFFFu) ^ tag)
                                  | (((u32)(g2 >> 16) & 0xFFFFu) ^ tag)
                                  | (((u32)(g3 >> 16) & 0xFFFFu) ^ tag);
                            if (b == 0u) {
                                f[4 * kc + 0] = g0; f[4 * kc + 1] = g1;
                                f[4 * kc + 2] = g2; f[4 * kc + 3] = g3;
                                bad &= ~(1u << kc);
                            }
                        }
                    }
                }
                __builtin_amdgcn_sched_barrier(0);
                // L0: poll completion drained prior stores; post out0(<s) ready
                if (LAYER == 0 && s >= 1) {
                    asm volatile("s_waitcnt vmcnt(0)" ::: "memory");
                    if (lane == 0) astore32(bcs, (u32)s);
                }
                // acc starts from A-wave's part (scr[s&1], written last iteration)
                f32x4 acc[4];
                #pragma unroll
                for (int g = 0; g < 4; ++g) acc[g] = scr[(size_t)(((s & 1) * 2 + m) * 4 + g) * 64 + lane];
                #pragma unroll
                for (int kc = 0; kc < 16; ++kc) {
                    u32 w0 = (u32)(f[4 * kc + 0] & 0xFFFFu) | ((u32)(f[4 * kc + 0] >> 32) << 16);
                    u32 w1 = (u32)(f[4 * kc + 1] & 0xFFFFu) | ((u32)(f[4 * kc + 1] >> 32) << 16);
                    u32 w2 = (u32)(f[4 * kc + 2] & 0xFFFFu) | ((u32)(f[4 * kc + 2] >> 32) << 16);
                    u32 w3 = (u32)(f[4 * kc + 3] & 0xFFFFu) | ((u32)(f[4 * kc + 3] >> 32) << 16);
                    u32x4 ww = {w0, w1, w2, w3};
                    bf16x8 a = __builtin_bit_cast(bf16x8, ww);
                    #pragma unroll
                    for (int g = 0; g < 4; ++g)
                        acc[g] = __builtin_amdgcn_mfma_f32_16x16x32_bf16(
                            a, *(const bf16x8*)(WBs + (size_t)(g * KCT + KCA + kc) * 512 + (size_t)lane * 8), acc[g], 0, 0, 0);
                }
                // ---- cell update ----
                const bool is_last = (s == T_ - 1);
                const int bb = (lane >> 4) << 2;
                #pragma unroll
                for (int r = 0; r < 4; ++r) {
                    const float vi = sigf(acc[0][r] + bi0);
                    const float vf = sigf(acc[1][r] + bi1);
                    const float vg = tanh_fast(acc[2][r] + bi2);
                    const float vo = sigf(acc[3][r] + bi3);
                    const float cn = vf * creg[r] + vi * vg;
                    creg[r] = cn;
                    const float hn = vo * tanh_fast(cn);
                    tileb[(size_t)(m * 16 + bb + r) * 20 + (lane & 15)] = f2bf(hn);
                    if (is_last) {
                        const int bg = mq * 32 + m * 16 + bb + r;
                        out[(LAYER ? 98304 : 32768) + bg * 512 + jl] = hn;
                        out[(LAYER ? 229376 : 163840) + bg * 512 + jl] = cn;
                    }
                }
                // ---- tagged h store (fire-and-forget) ----
                const u32 wtag = (u32)(s + 1);
                u32* hw = Hgrp + (size_t)(wtag & 1) * 16384 + (size_t)m * 8192;
                #pragma unroll
                for (int q = 0; q < 2; ++q) {
                    u32 w = *(const u32*)&tileb[(size_t)(m * 16 + (lane >> 2)) * 20 + q * 8 + (lane & 3) * 2];
                    u64 v = (u64)(w & 0xFFFFu) | ((u64)wtag << 16)
                          | ((u64)(w >> 16) << 32) | ((u64)wtag << 48);
                    astore((u64*)(hw + (size_t)(js >> 1) * 512 + (size_t)((js & 1) * 2 + q) * 128
                                  + (size_t)(lane >> 2) * 8 + (size_t)((lane & 3) * 2)), v);
                }
                if (LAYER == 0) {
                    const int q2 = lane >> 5, lw = lane & 31, b2 = lw >> 1, e4 = (lw & 1) * 4;
                    u64 v = *(const u64*)&tileb[(size_t)(m * 16 + b2) * 20 + q2 * 8 + e4];
                    astore((u64*)(Out0 + (size_t)s * 65536 + (size_t)(2 * mq + m) * 8192
                                  + (size_t)(js >> 1) * 512 + (size_t)((js & 1) * 2 + q2) * 128
                                  + (size_t)b2 * 8 + (size_t)e4), v);
                }
            }
            __syncthreads();
        }
        // epilogue: final out0 flag (out0(T-1))
        if (LAYER == 0) {
            asm volatile("s_waitcnt vmcnt(0)" ::: "memory");
            if (lane == 0) astore32(bcs, (u32)(T_ + 1));
        }
    }
}

__global__ __launch_bounds__(256, 1) void lstm_persistent(
    const u16* __restrict__ Xswz, u16* __restrict__ Out0swz,
    const u16* __restrict__ WB0, const u16* __restrict__ WB1,
    const float* __restrict__ bsum0, const float* __restrict__ bsum1,
    u32* __restrict__ Htag, float* __restrict__ out, u32* __restrict__ bc)
{
    __shared__ u16 WBs[4 * 32 * 512];                 // 128 KB
    __shared__ f32x4 scr[2 * 2 * 4 * 64];             // 16 KB
    __shared__ __align__(16) u16 tileb[2 * 16 * 20];  // 1.25 KB

    const int bid = blockIdx.x;
    const int g = bid & 7, js = bid >> 3;
    const int layer = g >> 2, mq = g & 3;
    const int tid = threadIdx.x;
    const int wid = tid >> 6, lane = tid & 63;

    const int KCtot = layer ? 32 : 24;
    const u16* WB = layer ? WB1 : WB0;
    for (int gg = 0; gg < 4; ++gg) {
        const u32x4* s4 = (const u32x4*)(WB + ((size_t)(gg * 32 + js) * KCtot) * 512);
        u32x4* d4 = (u32x4*)(WBs + (size_t)gg * KCtot * 512);
        for (int i = tid; i < KCtot * 64; i += 256) d4[i] = s4[i];
    }
    __syncthreads();

    u32* Hgrp = Htag + (size_t)g * 32768;   // [2 buf][2 m][16 kc][512]
    u32* bcg = bc + mq * 64;                // [2 m][32 js]

    if (layer == 0)
        run_loop<0>(Xswz, Out0swz, WBs, scr, tileb, Hgrp, bsum0, out, bcg, js, mq, wid, lane);
    else
        run_loop<1>(Xswz, Out0swz, WBs, scr, tileb, Hgrp, bsum1, out, bcg, js, mq, wid, lane);
}

// ---------- tail: logits ----------
__device__ __forceinline__ float dot4_(float4 a, float4 w, float s) {
    s = fmaf(a.x, w.x, s); s = fmaf(a.y, w.y, s);
    s = fmaf(a.z, w.z, s); s = fmaf(a.w, w.w, s);
    return s;
}

__global__ __launch_bounds__(256) void logits_kernel(
    const float* __restrict__ h1, const float* __restrict__ fc_w,
    const float* __restrict__ fc_b, float* __restrict__ out)
{
    __shared__ float hs[H_];
    const int b = blockIdx.x;
    for (int k = threadIdx.x; k < H_; k += 256) hs[k] = h1[(size_t)b * H_ + k];
    __syncthreads();
    const int v = threadIdx.x;
    const float4* wr = reinterpret_cast<const float4*>(fc_w + (size_t)v * H_);
    const float4* hr = reinterpret_cast<const float4*>(hs);
    float s = 0.f;
    #pragma unroll 8
    for (int k = 0; k < H_ / 4; ++k) s = dot4_(hr[k], wr[k], s);
    out[(size_t)b * V_ + v] = s + fc_b[v];
}

extern "C" void kernel_launch(void* const* d_in, const int* in_sizes, int n_in,
                              void* d_out, int out_size, void* d_ws, size_t ws_size,
                              hipStream_t stream) {
    const float* x     = (const float*)d_in[0];
    const float* w_ih0 = (const float*)d_in[1];
    const float* w_hh0 = (const float*)d_in[2];
    const float* b_ih0 = (const float*)d_in[3];
    const float* b_hh0 = (const float*)d_in[4];
    const float* w_ih1 = (const float*)d_in[5];
    const float* w_hh1 = (const float*)d_in[6];
    const float* b_ih1 = (const float*)d_in[7];
    const float* b_hh1 = (const float*)d_in[8];
    const float* fc_w  = (const float*)d_in[9];
    const float* fc_b  = (const float*)d_in[10];
    float* out = (float*)d_out;

    // ---- workspace carve-up ----
    char* p = (char*)d_ws;
    u16* Xswz    = (u16*)p; p += (size_t)512 * 32768 * 2;          // 32 MB
    u16* Out0swz = (u16*)p; p += (size_t)512 * 65536 * 2;          // 64 MB
    u16* WB0     = (u16*)p; p += (size_t)128 * 24 * 512 * 2;       // 3 MB
    u16* WB1     = (u16*)p; p += (size_t)128 * 32 * 512 * 2;       // 4 MB
    u32* Htag    = (u32*)p; p += (size_t)8 * 32768 * 4;            // 1 MB
    float* bsum0 = (float*)p; p += 2048 * 4;
    float* bsum1 = (float*)p; p += 2048 * 4;
    u32* bc      = (u32*)p;  p += 4 * 64 * 4;                      // 1 KB

    // ---- init + operand re-layout (graph-replayed each call) ----
    hipMemsetAsync(Htag, 0, (size_t)8 * 32768 * 4, stream);        // tag 0 == h(-1)=0 ready
    hipMemsetAsync(bc, 0, 4 * 64 * 4, stream);
    conv_x<<<65536, 256, 0, stream>>>(Xswz, x);
    conv_w<<<(2048 * 768) / 256, 256, 0, stream>>>(WB0, w_ih0, w_hh0, 256, 768);
    conv_w<<<(2048 * 1024) / 256, 256, 0, stream>>>(WB1, w_ih1, w_hh1, 512, 1024);
    vadd<<<8, 256, 0, stream>>>(bsum0, b_ih0, b_hh0, 2048);
    vadd<<<8, 256, 0, stream>>>(bsum1, b_ih1, b_hh1, 2048);

    // ---- persistent pipelined recurrence: one dispatch ----
    lstm_persistent<<<256, 256, 0, stream>>>(
        Xswz, Out0swz, WB0, WB1, bsum0, bsum1, Htag, out, bc);

    logits_kernel<<<B_, 256, 0, stream>>>(out + 98304, fc_w, fc_b, out);
}

// Round 10
// 2665.099 us; speedup vs baseline: 1.4325x; 1.4325x over previous
//
#include <hip/hip_runtime.h>
#include <math.h>

#define B_ 128
#define T_ 512
#define V_ 256
#define H_ 512

typedef unsigned short u16;
typedef unsigned int u32;
typedef unsigned long long u64;
typedef __attribute__((ext_vector_type(8))) __bf16 bf16x8;
typedef __attribute__((ext_vector_type(4))) float f32x4;
typedef __attribute__((ext_vector_type(4))) u32 u32x4;

__device__ __forceinline__ float sigf(float x) { return 1.f / (1.f + __expf(-x)); }
__device__ __forceinline__ float tanh_fast(float x) {
    x = fminf(fmaxf(x, -15.f), 15.f);
    float e = __expf(2.f * x);
    return (e - 1.f) / (e + 1.f);
}
__device__ __forceinline__ u16 f2bf(float f) {
    union { float f; u32 u; } v; v.f = f;
    u32 r = v.u + 0x7FFFu + ((v.u >> 16) & 1u);
    return (u16)(r >> 16);
}

// proven cross-XCD visibility path: compiler-generated relaxed agent atomics
__device__ __forceinline__ u64 aload(const u64* p) {
    return __hip_atomic_load(p, __ATOMIC_RELAXED, __HIP_MEMORY_SCOPE_AGENT);
}
__device__ __forceinline__ void astore(u64* p, u64 v) {
    __hip_atomic_store(p, v, __ATOMIC_RELAXED, __HIP_MEMORY_SCOPE_AGENT);
}
__device__ __forceinline__ u32 aload32(const u32* p) {
    return __hip_atomic_load(p, __ATOMIC_RELAXED, __HIP_MEMORY_SCOPE_AGENT);
}
__device__ __forceinline__ void astore32(u32* p, u32 v) {
    __hip_atomic_store(p, v, __ATOMIC_RELAXED, __HIP_MEMORY_SCOPE_AGENT);
}
__device__ __forceinline__ void pollge(const u32* slots, int idx, int target) {
    const u32* p = slots + idx;
    for (;;) {
        u32 v = aload32(p);
        if (__all((int)v >= target)) break;
        __builtin_amdgcn_s_sleep(1);
    }
    __builtin_amdgcn_sched_barrier(0);
    asm volatile("" ::: "memory");
}
__device__ __forceinline__ bf16x8 afrag(const u16* p) {
    union { u64 d[2]; bf16x8 v; } u;
    u.d[0] = aload((const u64*)p);
    u.d[1] = aload((const u64*)(p + 4));
    return u.v;
}

// ---------- prep kernels (verified rounds 2-9) ----------
__global__ __launch_bounds__(256) void conv_x(u16* __restrict__ dst, const float* __restrict__ x) {
    int tid = blockIdx.x * 256 + threadIdx.x;
    int k = tid & (V_ - 1);
    int t = (tid >> 8) & (T_ - 1);
    int b = tid >> 17;
    float v = x[tid];
    int lane = (b & 15) | (((k >> 3) & 3) << 4);
    dst[((((size_t)t * 8 + (b >> 4)) * 8) + (k >> 5)) * 512 + (size_t)lane * 8 + (k & 7)] = f2bf(v);
}

__global__ __launch_bounds__(256) void conv_w(u16* __restrict__ dst,
                                              const float* __restrict__ wih,
                                              const float* __restrict__ whh,
                                              int KIN, int Ktot) {
    int tid = blockIdx.x * 256 + threadIdx.x;
    int n = tid / Ktot, k = tid - n * Ktot;
    float v = (k < KIN) ? wih[(size_t)n * KIN + k] : whh[(size_t)n * H_ + (k - KIN)];
    int lane = (n & 15) | (((k >> 3) & 3) << 4);
    dst[((size_t)((n >> 4) * (Ktot >> 5) + (k >> 5))) * 512 + (size_t)lane * 8 + (k & 7)] = f2bf(v);
}

__global__ __launch_bounds__(256) void vadd(float* __restrict__ d,
                                            const float* __restrict__ a,
                                            const float* __restrict__ b, int n) {
    int i = blockIdx.x * 256 + threadIdx.x;
    if (i < n) d[i] = a[i] + b[i];
}

// ---------- persistent recurrence ----------
// 256 blocks x 256 threads. blockIdx = js*8 + g, g = layer*4 + mq.
// Waves: wid 0,1 = A-role (m=wid): compute x/out0 part for step s+1 into
// scr[(s+1)&1] (one step AHEAD). wid 2,3 = H-role (m=wid-2): chunked tagged-h
// pipeline (4 chunks x 4 kc: issue next / verify+retry cur / MFMA cur),
// cell update, tagged h stores. ONE __syncthreads per step.
// h element = u32 (tag<<16 | bf16); u64 store => per-u64 tag consistency.
// h(t) tagged t+1 in buffer (t+1)&1; consumer at step s expects tag s.

template <int LAYER>
__device__ __forceinline__ void run_loop(
    const u16* __restrict__ Xswz, u16* __restrict__ Out0,
    const u16* __restrict__ WBs,          // LDS [4 g][KCT][512] bf16
    f32x4* __restrict__ scr,              // LDS [2 par][2 m][4 g][64]
    u16* __restrict__ tileb,              // LDS [2 m][16][20]
    u32* __restrict__ Hgrp,               // [2 buf][2 m][16 kc][512] tagged u32
    const float* __restrict__ bsum, float* __restrict__ out,
    u32* __restrict__ bc,                 // [2 m][32 js] (this mq)
    int js, int mq, int wid, int lane)
{
    constexpr int KCA = LAYER ? 16 : 8;
    constexpr int KCT = KCA + 16;
    const int m = wid & 1;
    const bool isA = wid < 2;
    const int jl = (js << 4) | (lane & 15);

    if (isA) {
        // ---------------- A-role: one step ahead ----------------
        for (int s = -1; s < T_; ++s) {
            const int tc = s + 1;
            if (tc < T_) {
                f32x4 acc[4];
                #pragma unroll
                for (int g = 0; g < 4; ++g) acc[g] = (f32x4){0.f, 0.f, 0.f, 0.f};
                if (LAYER == 0) {
                    const u16* As = Xswz + (size_t)tc * 32768 + (size_t)(2 * mq + m) * 4096 + (size_t)lane * 8;
                    #pragma unroll
                    for (int kc = 0; kc < 8; ++kc) {
                        bf16x8 a = *(const bf16x8*)(As + (size_t)kc * 512);
                        #pragma unroll
                        for (int g = 0; g < 4; ++g)
                            acc[g] = __builtin_amdgcn_mfma_f32_16x16x32_bf16(
                                a, *(const bf16x8*)(WBs + (size_t)(g * KCT + kc) * 512 + (size_t)lane * 8), acc[g], 0, 0, 0);
                    }
                } else {
                    pollge(bc + m * 32, lane & 31, tc + 1);   // out0(tc) ready
                    const u16* As = Out0 + (size_t)tc * 65536 + (size_t)(2 * mq + m) * 8192 + (size_t)lane * 8;
                    bf16x8 fa[16];
                    #pragma unroll
                    for (int kc = 0; kc < 16; ++kc) fa[kc] = afrag(As + (size_t)kc * 512);
                    #pragma unroll
                    for (int kc = 0; kc < 16; ++kc) {
                        #pragma unroll
                        for (int g = 0; g < 4; ++g)
                            acc[g] = __builtin_amdgcn_mfma_f32_16x16x32_bf16(
                                fa[kc], *(const bf16x8*)(WBs + (size_t)(g * KCT + kc) * 512 + (size_t)lane * 8), acc[g], 0, 0, 0);
                    }
                }
                #pragma unroll
                for (int g = 0; g < 4; ++g) scr[(size_t)(((tc & 1) * 2 + m) * 4 + g) * 64 + lane] = acc[g];
            }
            __syncthreads();
        }
    } else {
        // ---------------- H-role: chunked tagged pipeline ----------------
        const float bi0 = bsum[jl], bi1 = bsum[512 + jl];
        const float bi2 = bsum[1024 + jl], bi3 = bsum[1536 + jl];
        f32x4 creg = {0.f, 0.f, 0.f, 0.f};
        u32* bcs = bc + m * 32 + js;

        for (int s = -1; s < T_; ++s) {
            if (s >= 0) {
                const u32 tag = (u32)s;
                const u32* hb = Hgrp + (size_t)(tag & 1) * 16384 + (size_t)m * 8192;

                // acc init from A-wave's part (scr[s&1], written last iteration)
                f32x4 acc[4];
                #pragma unroll
                for (int g = 0; g < 4; ++g) acc[g] = scr[(size_t)(((s & 1) * 2 + m) * 4 + g) * 64 + lane];

                u64 fa[16], fb[16];
                // prologue: issue chunk 0 (kc 0..3)
                #pragma unroll
                for (int i = 0; i < 16; ++i)
                    fa[i] = aload((const u64*)(hb + (size_t)(i >> 2) * 512 + (size_t)lane * 8) + (i & 3));

                #pragma unroll
                for (int c = 0; c < 4; ++c) {
                    u64* cur = (c & 1) ? fb : fa;
                    u64* nxt = (c & 1) ? fa : fb;
                    if (c < 3) {
                        #pragma unroll
                        for (int i = 0; i < 16; ++i)
                            nxt[i] = aload((const u64*)(hb + (size_t)((c + 1) * 4 + (i >> 2)) * 512 + (size_t)lane * 8) + (i & 3));
                    }
                    // verify chunk c (waits only its own loads); retry 8KB chunk if stale
                    for (;;) {
                        u32 bad = 0u;
                        #pragma unroll
                        for (int i = 0; i < 16; ++i) bad |= (((u32)(cur[i] >> 16)) & 0xFFFFu) ^ tag;
                        if (!__any(bad != 0u)) break;
                        #pragma unroll
                        for (int i = 0; i < 16; ++i)
                            cur[i] = aload((const u64*)(hb + (size_t)(c * 4 + (i >> 2)) * 512 + (size_t)lane * 8) + (i & 3));
                    }
                    // MFMA chunk c (runs while chunk c+1 is in flight)
                    #pragma unroll
                    for (int k2 = 0; k2 < 4; ++k2) {
                        const u64 g0 = cur[4 * k2 + 0], g1 = cur[4 * k2 + 1];
                        const u64 g2 = cur[4 * k2 + 2], g3 = cur[4 * k2 + 3];
                        u32 w0 = (u32)(g0 & 0xFFFFu) | ((u32)(g0 >> 32) << 16);
                        u32 w1 = (u32)(g1 & 0xFFFFu) | ((u32)(g1 >> 32) << 16);
                        u32 w2 = (u32)(g2 & 0xFFFFu) | ((u32)(g2 >> 32) << 16);
                        u32 w3 = (u32)(g3 & 0xFFFFu) | ((u32)(g3 >> 32) << 16);
                        u32x4 ww = {w0, w1, w2, w3};
                        bf16x8 a = __builtin_bit_cast(bf16x8, ww);
                        const int kc = 4 * c + k2;
                        #pragma unroll
                        for (int g = 0; g < 4; ++g)
                            acc[g] = __builtin_amdgcn_mfma_f32_16x16x32_bf16(
                                a, *(const bf16x8*)(WBs + (size_t)(g * KCT + KCA + kc) * 512 + (size_t)lane * 8), acc[g], 0, 0, 0);
                    }
                }

                // L0: by now vmcnt drained all of last step's stores -> post out0 flag
                if (LAYER == 0 && s >= 1) {
                    asm volatile("s_waitcnt vmcnt(0)" ::: "memory");
                    if (lane == 0) astore32(bcs, (u32)s);
                }

                // ---- cell update ----
                const bool is_last = (s == T_ - 1);
                const int bb = (lane >> 4) << 2;
                #pragma unroll
                for (int r = 0; r < 4; ++r) {
                    const float vi = sigf(acc[0][r] + bi0);
                    const float vf = sigf(acc[1][r] + bi1);
                    const float vg = tanh_fast(acc[2][r] + bi2);
                    const float vo = sigf(acc[3][r] + bi3);
                    const float cn = vf * creg[r] + vi * vg;
                    creg[r] = cn;
                    const float hn = vo * tanh_fast(cn);
                    tileb[(size_t)(m * 16 + bb + r) * 20 + (lane & 15)] = f2bf(hn);
                    if (is_last) {
                        const int bg = mq * 32 + m * 16 + bb + r;
                        out[(LAYER ? 98304 : 32768) + bg * 512 + jl] = hn;
                        out[(LAYER ? 229376 : 163840) + bg * 512 + jl] = cn;
                    }
                }
                // ---- tagged h store (fire-and-forget) ----
                const u32 wtag = (u32)(s + 1);
                u32* hw = Hgrp + (size_t)(wtag & 1) * 16384 + (size_t)m * 8192;
                #pragma unroll
                for (int q = 0; q < 2; ++q) {
                    u32 w = *(const u32*)&tileb[(size_t)(m * 16 + (lane >> 2)) * 20 + q * 8 + (lane & 3) * 2];
                    u64 v = (u64)(w & 0xFFFFu) | ((u64)wtag << 16)
                          | ((u64)(w >> 16) << 32) | ((u64)wtag << 48);
                    astore((u64*)(hw + (size_t)(js >> 1) * 512 + (size_t)((js & 1) * 2 + q) * 128
                                  + (size_t)(lane >> 2) * 8 + (size_t)((lane & 3) * 2)), v);
                }
                if (LAYER == 0) {
                    const int q2 = lane >> 5, lw = lane & 31, b2 = lw >> 1, e4 = (lw & 1) * 4;
                    u64 v = *(const u64*)&tileb[(size_t)(m * 16 + b2) * 20 + q2 * 8 + e4];
                    astore((u64*)(Out0 + (size_t)s * 65536 + (size_t)(2 * mq + m) * 8192
                                  + (size_t)(js >> 1) * 512 + (size_t)((js & 1) * 2 + q2) * 128
                                  + (size_t)b2 * 8 + (size_t)e4), v);
                }
            }
            __syncthreads();
        }
        // epilogue: final out0 flag (covers out0(T-1))
        if (LAYER == 0) {
            asm volatile("s_waitcnt vmcnt(0)" ::: "memory");
            if (lane == 0) astore32(bcs, (u32)(T_ + 1));
        }
    }
}

__global__ __launch_bounds__(256, 1) void lstm_persistent(
    const u16* __restrict__ Xswz, u16* __restrict__ Out0swz,
    const u16* __restrict__ WB0, const u16* __restrict__ WB1,
    const float* __restrict__ bsum0, const float* __restrict__ bsum1,
    u32* __restrict__ Htag, float* __restrict__ out, u32* __restrict__ bc)
{
    __shared__ u16 WBs[4 * 32 * 512];                 // 128 KB
    __shared__ f32x4 scr[2 * 2 * 4 * 64];             // 16 KB
    __shared__ __align__(16) u16 tileb[2 * 16 * 20];  // 1.25 KB

    const int bid = blockIdx.x;
    const int g = bid & 7, js = bid >> 3;
    const int layer = g >> 2, mq = g & 3;
    const int tid = threadIdx.x;
    const int wid = tid >> 6, lane = tid & 63;

    const int KCtot = layer ? 32 : 24;
    const u16* WB = layer ? WB1 : WB0;
    for (int gg = 0; gg < 4; ++gg) {
        const u32x4* s4 = (const u32x4*)(WB + ((size_t)(gg * 32 + js) * KCtot) * 512);
        u32x4* d4 = (u32x4*)(WBs + (size_t)gg * KCtot * 512);
        for (int i = tid; i < KCtot * 64; i += 256) d4[i] = s4[i];
    }
    __syncthreads();

    u32* Hgrp = Htag + (size_t)g * 32768;   // [2 buf][2 m][16 kc][512]
    u32* bcg = bc + mq * 64;                // [2 m][32 js]

    if (layer == 0)
        run_loop<0>(Xswz, Out0swz, WBs, scr, tileb, Hgrp, bsum0, out, bcg, js, mq, wid, lane);
    else
        run_loop<1>(Xswz, Out0swz, WBs, scr, tileb, Hgrp, bsum1, out, bcg, js, mq, wid, lane);
}

// ---------- tail: logits ----------
__device__ __forceinline__ float dot4_(float4 a, float4 w, float s) {
    s = fmaf(a.x, w.x, s); s = fmaf(a.y, w.y, s);
    s = fmaf(a.z, w.z, s); s = fmaf(a.w, w.w, s);
    return s;
}

__global__ __launch_bounds__(256) void logits_kernel(
    const float* __restrict__ h1, const float* __restrict__ fc_w,
    const float* __restrict__ fc_b, float* __restrict__ out)
{
    __shared__ float hs[H_];
    const int b = blockIdx.x;
    for (int k = threadIdx.x; k < H_; k += 256) hs[k] = h1[(size_t)b * H_ + k];
    __syncthreads();
    const int v = threadIdx.x;
    const float4* wr = reinterpret_cast<const float4*>(fc_w + (size_t)v * H_);
    const float4* hr = reinterpret_cast<const float4*>(hs);
    float s = 0.f;
    #pragma unroll 8
    for (int k = 0; k < H_ / 4; ++k) s = dot4_(hr[k], wr[k], s);
    out[(size_t)b * V_ + v] = s + fc_b[v];
}

extern "C" void kernel_launch(void* const* d_in, const int* in_sizes, int n_in,
                              void* d_out, int out_size, void* d_ws, size_t ws_size,
                              hipStream_t stream) {
    const float* x     = (const float*)d_in[0];
    const float* w_ih0 = (const float*)d_in[1];
    const float* w_hh0 = (const float*)d_in[2];
    const float* b_ih0 = (const float*)d_in[3];
    const float* b_hh0 = (const float*)d_in[4];
    const float* w_ih1 = (const float*)d_in[5];
    const float* w_hh1 = (const float*)d_in[6];
    const float* b_ih1 = (const float*)d_in[7];
    const float* b_hh1 = (const float*)d_in[8];
    const float* fc_w  = (const float*)d_in[9];
    const float* fc_b  = (const float*)d_in[10];
    float* out = (float*)d_out;

    // ---- workspace carve-up ----
    char* p = (char*)d_ws;
    u16* Xswz    = (u16*)p; p += (size_t)512 * 32768 * 2;          // 32 MB
    u16* Out0swz = (u16*)p; p += (size_t)512 * 65536 * 2;          // 64 MB
    u16* WB0     = (u16*)p; p += (size_t)128 * 24 * 512 * 2;       // 3 MB
    u16* WB1     = (u16*)p; p += (size_t)128 * 32 * 512 * 2;       // 4 MB
    u32* Htag    = (u32*)p; p += (size_t)8 * 32768 * 4;            // 1 MB
    float* bsum0 = (float*)p; p += 2048 * 4;
    float* bsum1 = (float*)p; p += 2048 * 4;
    u32* bc      = (u32*)p;  p += 4 * 64 * 4;                      // 1 KB

    // ---- init + operand re-layout (graph-replayed each call) ----
    hipMemsetAsync(Htag, 0, (size_t)8 * 32768 * 4, stream);        // tag 0 == h(-1)=0 ready
    hipMemsetAsync(bc, 0, 4 * 64 * 4, stream);
    conv_x<<<65536, 256, 0, stream>>>(Xswz, x);
    conv_w<<<(2048 * 768) / 256, 256, 0, stream>>>(WB0, w_ih0, w_hh0, 256, 768);
    conv_w<<<(2048 * 1024) / 256, 256, 0, stream>>>(WB1, w_ih1, w_hh1, 512, 1024);
    vadd<<<8, 256, 0, stream>>>(bsum0, b_ih0, b_hh0, 2048);
    vadd<<<8, 256, 0, stream>>>(bsum1, b_ih1, b_hh1, 2048);

    // ---- persistent pipelined recurrence: one dispatch ----
    lstm_persistent<<<256, 256, 0, stream>>>(
        Xswz, Out0swz, WB0, WB1, bsum0, bsum1, Htag, out, bc);

    logits_kernel<<<B_, 256, 0, stream>>>(out + 98304, fc_w, fc_b, out);
}